// Round 7
// baseline (516.066 us; speedup 1.0000x reference)
//
#include <hip/hip_runtime.h>

// Problem constants (match reference setup_inputs)
#define FF 8
#define BB 4096
#define VV 100000
#define DD 128
#define NN 81920

// One wave (64 lanes) per (feature, bag). Wave splits into two 32-lane
// halves; each half reads one full D=128 row per float4 load (32 x 16B =
// 512B), i.e. 2 rows per dwordx4 instruction. Rows processed in fully
// predicated blocks of 8 (4 independent loads = 4KB in flight per wave;
// dead slots re-load slot 0 of the chunk -> L1 hit, weight 0). Indices come
// from ONE vector load per 64 rows, broadcast per-row via __shfl.
// vs R5: blocks of 8 instead of 16, launch_bounds(256,8) -> 32 waves/CU
// (2x the waves, same aggregate outstanding bytes) to test whether
// wave-level parallelism, not per-wave MLP, is the binding constraint.
__global__ __launch_bounds__(256, 8) void ebc_pool_kernel(
    const int* __restrict__ values,   // [F, N]
    const int* __restrict__ offsets,  // [F, B+1]
    const float* __restrict__ tables, // [F, V, D]
    float* __restrict__ out)          // [B, F*D]
{
    const int wave = threadIdx.x >> 6;             // 0..3
    const int lane = threadIdx.x & 63;
    const int half = lane >> 5;                    // 0 or 1
    const int hl   = lane & 31;                    // lane within half

    // XCD-aware swizzle: feature = blockIdx % 8 -> each XCD's L2 mostly
    // serves a single table (unique/table 28.6MB vs 4MB L2, ~14% hit).
    const int f = blockIdx.x & 7;
    const int b = ((blockIdx.x >> 3) << 2) + wave; // bag id in [0, BB)

    const int* __restrict__ offs = offsets + f * (BB + 1);
    const int start = __builtin_amdgcn_readfirstlane(offs[b]);
    const int end   = __builtin_amdgcn_readfirstlane(offs[b + 1]);

    const int* __restrict__ vals = values + f * NN;
    const float* __restrict__ tab = tables + (size_t)f * (VV * DD);

    float4 acc0 = make_float4(0.f, 0.f, 0.f, 0.f);
    float4 acc1 = make_float4(0.f, 0.f, 0.f, 0.f);

    for (int c0 = start; c0 < end; c0 += 64) {
        // one vector load fetches this chunk's indices (clamped, no OOB)
        int g = c0 + lane;
        g = (g < end) ? g : (end - 1);
        const int idxv = vals[g];

        const int rem = end - c0;
        const int nch = (rem < 64) ? rem : 64;     // uniform chunk length

        for (int r = 0; r < nch; r += 8) {         // uniform trip count
#define EBC_ROW(k)                                                           \
            const int   rr##k = r + 2 * (k) + half;                          \
            const int   ok##k = rr##k < nch;                                 \
            const int   rc##k = ok##k ? rr##k : 0;                           \
            const int   id##k = __shfl(idxv, rc##k, 64);                     \
            const float w##k  = ok##k ? 1.f : 0.f;                           \
            const float4 v##k = ((const float4*)(tab + (size_t)id##k * DD))[hl];
            EBC_ROW(0) EBC_ROW(1) EBC_ROW(2) EBC_ROW(3)
#undef EBC_ROW
            acc0.x += w0 * v0.x + w1 * v1.x;
            acc0.y += w0 * v0.y + w1 * v1.y;
            acc0.z += w0 * v0.z + w1 * v1.z;
            acc0.w += w0 * v0.w + w1 * v1.w;
            acc1.x += w2 * v2.x + w3 * v3.x;
            acc1.y += w2 * v2.y + w3 * v3.y;
            acc1.z += w2 * v2.z + w3 * v3.z;
            acc1.w += w2 * v2.w + w3 * v3.w;
        }
    }

    acc0.x += acc1.x; acc0.y += acc1.y; acc0.z += acc1.z; acc0.w += acc1.w;

    // combine halves: lanes (hl, hl+32) hold the same 4 dims
    acc0.x += __shfl_xor(acc0.x, 32, 64);
    acc0.y += __shfl_xor(acc0.y, 32, 64);
    acc0.z += __shfl_xor(acc0.z, 32, 64);
    acc0.w += __shfl_xor(acc0.w, 32, 64);

    if (half == 0) {
        float4* __restrict__ o =
            (float4*)(out + (size_t)b * (FF * DD) + f * DD);
        o[hl] = acc0;
    }
}

extern "C" void kernel_launch(void* const* d_in, const int* in_sizes, int n_in,
                              void* d_out, int out_size, void* d_ws, size_t ws_size,
                              hipStream_t stream) {
    const int*   values  = (const int*)d_in[0];    // [F, N] int32
    const int*   offsets = (const int*)d_in[1];    // [F, B+1] int32
    const float* tables  = (const float*)d_in[2];  // [F, V, D] float32
    float*       out     = (float*)d_out;          // [B, F*D] float32

    const int total_bags = FF * BB;                // 32768
    const int blocks = total_bags / 4;             // 8192 blocks of 256 threads
    ebc_pool_kernel<<<blocks, 256, 0, stream>>>(values, offsets, tables, out);
}

// Round 9
// 507.833 us; speedup vs baseline: 1.0162x; 1.0162x over previous
//
#include <hip/hip_runtime.h>

// Problem constants (match reference setup_inputs)
#define FF 8
#define BB 4096
#define VV 100000
#define DD 128
#define NN 81920

// FINAL (= R5 best-measured config, 508.5 us headline).
// One wave (64 lanes) per (feature, bag). Wave splits into two 32-lane
// halves; each half reads one full D=128 row per float4 load (32 x 16B =
// 512B), so each dwordx4 instruction covers 2 rows. Rows are processed in
// fully-predicated blocks of 16 (8 independent loads = 8KB in flight per
// wave, even in the tail: dead slots re-load slot 0 of the chunk -> L1 hit,
// weight 0). Indices come from ONE vector load per 64 rows, broadcast
// per-row via __shfl -- zero per-row index memory traffic.
// launch_bounds(256,4): 16 waves/CU x 8KB outstanding = 128KB/CU in flight.
// Measured A/B (R7): 32 waves/CU x 4KB was NOT better -> keep this.
__global__ __launch_bounds__(256, 4) void ebc_pool_kernel(
    const int* __restrict__ values,   // [F, N]
    const int* __restrict__ offsets,  // [F, B+1]
    const float* __restrict__ tables, // [F, V, D]
    float* __restrict__ out)          // [B, F*D]
{
    const int wave = threadIdx.x >> 6;             // 0..3
    const int lane = threadIdx.x & 63;
    const int half = lane >> 5;                    // 0 or 1
    const int hl   = lane & 31;                    // lane within half

    // XCD-aware swizzle: feature = blockIdx % 8 -> each XCD's L2 mostly
    // serves a single table.
    const int f = blockIdx.x & 7;
    const int b = ((blockIdx.x >> 3) << 2) + wave; // bag id in [0, BB)

    const int* __restrict__ offs = offsets + f * (BB + 1);
    const int start = __builtin_amdgcn_readfirstlane(offs[b]);
    const int end   = __builtin_amdgcn_readfirstlane(offs[b + 1]);

    const int* __restrict__ vals = values + f * NN;
    const float* __restrict__ tab = tables + (size_t)f * (VV * DD);

    float4 acc0 = make_float4(0.f, 0.f, 0.f, 0.f);
    float4 acc1 = make_float4(0.f, 0.f, 0.f, 0.f);

    for (int c0 = start; c0 < end; c0 += 64) {
        // one vector load fetches this chunk's indices (clamped, no OOB)
        int g = c0 + lane;
        g = (g < end) ? g : (end - 1);
        const int idxv = vals[g];

        const int rem = end - c0;
        const int nch = (rem < 64) ? rem : 64;     // uniform chunk length

        for (int r = 0; r < nch; r += 16) {        // uniform trip count
#define EBC_ROW(k)                                                           \
            const int   rr##k = r + 2 * (k) + half;                          \
            const int   ok##k = rr##k < nch;                                 \
            const int   rc##k = ok##k ? rr##k : 0;                           \
            const int   id##k = __shfl(idxv, rc##k, 64);                     \
            const float w##k  = ok##k ? 1.f : 0.f;                           \
            const float4 v##k = ((const float4*)(tab + (size_t)id##k * DD))[hl];
            EBC_ROW(0) EBC_ROW(1) EBC_ROW(2) EBC_ROW(3)
            EBC_ROW(4) EBC_ROW(5) EBC_ROW(6) EBC_ROW(7)
#undef EBC_ROW
            acc0.x += (w0 * v0.x + w1 * v1.x) + (w2 * v2.x + w3 * v3.x);
            acc0.y += (w0 * v0.y + w1 * v1.y) + (w2 * v2.y + w3 * v3.y);
            acc0.z += (w0 * v0.z + w1 * v1.z) + (w2 * v2.z + w3 * v3.z);
            acc0.w += (w0 * v0.w + w1 * v1.w) + (w2 * v2.w + w3 * v3.w);
            acc1.x += (w4 * v4.x + w5 * v5.x) + (w6 * v6.x + w7 * v7.x);
            acc1.y += (w4 * v4.y + w5 * v5.y) + (w6 * v6.y + w7 * v7.y);
            acc1.z += (w4 * v4.z + w5 * v5.z) + (w6 * v6.z + w7 * v7.z);
            acc1.w += (w4 * v4.w + w5 * v5.w) + (w6 * v6.w + w7 * v7.w);
        }
    }

    acc0.x += acc1.x; acc0.y += acc1.y; acc0.z += acc1.z; acc0.w += acc1.w;

    // combine halves: lanes (hl, hl+32) hold the same 4 dims
    acc0.x += __shfl_xor(acc0.x, 32, 64);
    acc0.y += __shfl_xor(acc0.y, 32, 64);
    acc0.z += __shfl_xor(acc0.z, 32, 64);
    acc0.w += __shfl_xor(acc0.w, 32, 64);

    if (half == 0) {
        float4* __restrict__ o =
            (float4*)(out + (size_t)b * (FF * DD) + f * DD);
        o[hl] = acc0;
    }
}

extern "C" void kernel_launch(void* const* d_in, const int* in_sizes, int n_in,
                              void* d_out, int out_size, void* d_ws, size_t ws_size,
                              hipStream_t stream) {
    const int*   values  = (const int*)d_in[0];    // [F, N] int32
    const int*   offsets = (const int*)d_in[1];    // [F, B+1] int32
    const float* tables  = (const float*)d_in[2];  // [F, V, D] float32
    float*       out     = (float*)d_out;          // [B, F*D] float32

    const int total_bags = FF * BB;                // 32768
    const int blocks = total_bags / 4;             // 8192 blocks of 256 threads
    ebc_pool_kernel<<<blocks, 256, 0, stream>>>(values, offsets, tables, out);
}